// Round 1
// baseline (28340.518 us; speedup 1.0000x reference)
//
#include <hip/hip_runtime.h>
#include <hip/hip_bf16.h>

#define B_ 32
#define T_ 512
#define D_ 1024
#define N_ 1024
#define NWG 192
#define NGATE 128
#define TPB 256
// LDS: weights [2][64][64][8] ushort = 131072 B, reduce 8 tiles*256 f32 = 8192 B, bias 64 B
#define SMEM_BYTES (131072 + 8192 + 64)

typedef __attribute__((ext_vector_type(8))) short short8v;
typedef __attribute__((ext_vector_type(4))) short short4v;
typedef __attribute__((ext_vector_type(4))) float f32x4;

__device__ __forceinline__ float bf2f(unsigned short u) {
  union { float f; unsigned int i; } c; c.i = ((unsigned int)u) << 16; return c.f;
}
__device__ __forceinline__ unsigned short f2bf(float f) {
  union { float f; unsigned int i; } c; c.f = f;
  unsigned int r = c.i + 0x7FFFu + ((c.i >> 16) & 1u);
  return (unsigned short)(r >> 16);
}

// Monotonic-counter grid barrier. ctrs zeroed by hipMemsetAsync each launch.
// Counters strided 64B to avoid cross-barrier false sharing.
__device__ __forceinline__ void gbar(unsigned* ctrs, int idx) {
  __syncthreads();  // drains vmcnt(0): all threads' stores complete to L2
  if (threadIdx.x == 0) {
    __threadfence();  // agent-scope release: make this XCD's L2 globally visible
    unsigned* c = ctrs + (size_t)idx * 16;
    __hip_atomic_fetch_add(c, 1u, __ATOMIC_ACQ_REL, __HIP_MEMORY_SCOPE_AGENT);
    int tries = 0;
    while (__hip_atomic_load(c, __ATOMIC_ACQUIRE, __HIP_MEMORY_SCOPE_AGENT) < NWG) {
      __builtin_amdgcn_s_sleep(1);
      if (++tries > (1 << 22)) break;  // safety valve: never hit in normal operation
    }
  }
  __syncthreads();
}

// One [32 x 16] output tile, K=2048 split over 4 waves; hi/lo split-bf16 weights.
// A-fragment (16x16x32 bf16): lane l holds A[m = l&15][k], k = {4*(l>>4)+j} for
// k-half 0..15 (elems 0-3) and 16 + 4*(l>>4)+j (elems 4-7). B symmetric with n=l&15.
// LDS weights are pre-arranged in exactly this fragment order.
__device__ __forceinline__ void mfma_tile(
    const unsigned short* __restrict__ srcA_lo,   // [32][1024], k < 1024 (x part)
    const unsigned short* __restrict__ srcA_hi,   // [32][1024], k >= 1024 (h or r*h)
    const unsigned short* ldsW, float* ldsR, int lane, int wv)
{
  const unsigned short* src = (wv < 2) ? srcA_lo : srcA_hi;
  const int kwbase = (wv & 1) * 512;
  const int kq = (lane >> 4) * 4;
#pragma unroll
  for (int mt = 0; mt < 2; ++mt) {
    const int m = mt * 16 + (lane & 15);
    const unsigned short* rowp = src + m * 1024 + kwbase;
    f32x4 a = {0.f, 0.f, 0.f, 0.f};
#pragma unroll
    for (int ks = 0; ks < 16; ++ks) {
      const int kl = ks * 32 + kq;
      short4v alo  = *(const short4v*)(rowp + kl);
      short4v ahi2 = *(const short4v*)(rowp + kl + 16);
      short8v av = __builtin_shufflevector(alo, ahi2, 0, 1, 2, 3, 4, 5, 6, 7);
      const int ksg = wv * 16 + ks;  // global k-step 0..63
      short8v bhi = *(const short8v*)(ldsW + ((size_t)(0 * 64 + ksg) * 64 + lane) * 8);
      short8v blo = *(const short8v*)(ldsW + ((size_t)(1 * 64 + ksg) * 64 + lane) * 8);
      a = __builtin_amdgcn_mfma_f32_16x16x32_bf16(av, bhi, a, 0, 0, 0);
      a = __builtin_amdgcn_mfma_f32_16x16x32_bf16(av, blo, a, 0, 0, 0);
    }
    // partial store: D layout col=lane&15, row=4*(lane>>4)+reg  [m89-verified]
#pragma unroll
    for (int r = 0; r < 4; ++r) {
      const int row = 4 * (lane >> 4) + r;
      ldsR[(wv * 2 + mt) * 256 + row * 16 + (lane & 15)] = a[r];
    }
  }
}

__global__ __launch_bounds__(TPB, 1) void gru_persistent(
    const float* __restrict__ x, const float* __restrict__ h0,
    const float* __restrict__ Wg, const float* __restrict__ bg,
    const float* __restrict__ Wc, const float* __restrict__ bc,
    float* __restrict__ out,
    unsigned* __restrict__ ctrs,
    unsigned short* __restrict__ xq,     // [2][32][1024] bf16 (double-buffered x_t)
    unsigned short* __restrict__ hq,     // [32][1024] bf16 h
    unsigned short* __restrict__ rhq,    // [32][1024] bf16 r*h
    float* __restrict__ u_buf,           // [32][1024] f32 u gate
    float* __restrict__ h_buf)           // [32][1024] f32 h
{
  const int wg = blockIdx.x;
  const int tid = threadIdx.x;
  const int lane = tid & 63;
  const int wv = tid >> 6;

  extern __shared__ char smem[];
  unsigned short* ldsW = (unsigned short*)smem;            // [2][64][64][8]
  float* ldsR = (float*)(smem + 131072);                   // [8][256]
  float* ldsBias = (float*)(smem + 131072 + 8192);         // [16]

  const bool is_gate = wg < NGATE;
  const int c0 = (is_gate ? wg : (wg - NGATE)) * 16;
  const float* Wsrc = is_gate ? Wg : Wc;
  const int ldw = is_gate ? 2 * N_ : N_;
  const float* bias = is_gate ? bg : bc;

  // ---- preload weight slice into LDS in MFMA-fragment order, hi/lo split bf16
  for (int i = tid; i < 64 * 64; i += TPB) {
    const int ks = i >> 6, l = i & 63;
    const int n = l & 15, kqp = (l >> 4) * 4;
#pragma unroll
    for (int j = 0; j < 8; ++j) {
      const int k = ks * 32 + ((j < 4) ? 0 : 16) + kqp + (j & 3);
      const float w = Wsrc[(size_t)k * ldw + c0 + n];
      const unsigned short hi = f2bf(w);
      const unsigned short lo = f2bf(w - bf2f(hi));
      ldsW[((size_t)(0 * 64 + ks) * 64 + l) * 8 + j] = hi;
      ldsW[((size_t)(1 * 64 + ks) * 64 + l) * 8 + j] = lo;
    }
  }
  if (tid < 16) ldsBias[tid] = bias[c0 + tid];

  // ---- init h/hq from h0 and xq[0] (done by gate WGs: wg*256+tid covers 0..32767)
  {
    const int gidx = wg * TPB + tid;
    if (gidx < B_ * N_) {
      const float hv = h0[gidx];
      h_buf[gidx] = hv;
      hq[gidx] = f2bf(hv);
      const int b = gidx >> 10, d = gidx & 1023;
      xq[gidx] = f2bf(x[((size_t)b * T_) * D_ + d]);
    }
  }
  gbar(ctrs, 0);

  for (int t = 0; t < T_; ++t) {
    if (is_gate) {
      // ---- phase 1: gates for columns [c0, c0+16)
      mfma_tile(xq + (t & 1) * (B_ * D_), hq, ldsW, ldsR, lane, wv);
      __syncthreads();
#pragma unroll
      for (int p = 0; p < 2; ++p) {
        const int rc = tid, mt = p;
        float s = ldsR[(0 * 2 + mt) * 256 + rc] + ldsR[(1 * 2 + mt) * 256 + rc]
                + ldsR[(2 * 2 + mt) * 256 + rc] + ldsR[(3 * 2 + mt) * 256 + rc];
        const int row = rc >> 4, col = rc & 15;
        const int b = mt * 16 + row;
        const int colg = c0 + col;
        float pre = s + ldsBias[col];
        pre = fminf(fmaxf(pre, -30.f), 30.f);
        const float g = 1.f / (1.f + __expf(-pre));
        if (c0 < N_) {                       // r columns -> write r*h (bf16)
          const float hv = h_buf[b * N_ + colg];
          rhq[b * N_ + colg] = f2bf(g * hv);
        } else {                             // u columns -> write u (f32)
          u_buf[b * N_ + (colg - N_)] = g;
        }
      }
      gbar(ctrs, 1 + 2 * t);
      // ---- overlap: prefetch/convert x_{t+1} while cand WGs compute
      if (t + 1 < T_) {
        const int gidx = wg * TPB + tid;     // exactly 0..32767 over 128 gate WGs
        const int b = gidx >> 10, d = gidx & 1023;
        xq[((t + 1) & 1) * (B_ * D_) + gidx] =
            f2bf(x[((size_t)b * T_ + (t + 1)) * D_ + d]);
      }
      gbar(ctrs, 2 + 2 * t);
    } else {
      gbar(ctrs, 1 + 2 * t);
      // ---- phase 2: candidate + h-update for columns [c0, c0+16)
      mfma_tile(xq + (t & 1) * (B_ * D_), rhq, ldsW, ldsR, lane, wv);
      __syncthreads();
#pragma unroll
      for (int p = 0; p < 2; ++p) {
        const int rc = tid, mt = p;
        float s = ldsR[(0 * 2 + mt) * 256 + rc] + ldsR[(1 * 2 + mt) * 256 + rc]
                + ldsR[(2 * 2 + mt) * 256 + rc] + ldsR[(3 * 2 + mt) * 256 + rc];
        const int row = rc >> 4, col = rc & 15;
        const int b = mt * 16 + row;
        const int colg = c0 + col;
        float pre = s + ldsBias[col];
        pre = fminf(fmaxf(pre, -20.f), 20.f);
        const float e = __expf(2.f * pre);
        const float cv = (e - 1.f) / (e + 1.f);   // tanh
        const int hidx = b * N_ + colg;
        const float hv = h_buf[hidx];
        const float uv = u_buf[hidx];
        const float hn = uv * hv + (1.f - uv) * cv;
        h_buf[hidx] = hn;
        hq[hidx] = f2bf(hn);
        out[((size_t)b * T_ + t) * N_ + colg] = hn;
      }
      gbar(ctrs, 2 + 2 * t);
    }
  }
}

extern "C" void kernel_launch(void* const* d_in, const int* in_sizes, int n_in,
                              void* d_out, int out_size, void* d_ws, size_t ws_size,
                              hipStream_t stream) {
  const float* x  = (const float*)d_in[0];
  const float* h0 = (const float*)d_in[1];
  const float* Wg = (const float*)d_in[2];
  const float* bg = (const float*)d_in[3];
  const float* Wc = (const float*)d_in[4];
  const float* bc = (const float*)d_in[5];
  float* out = (float*)d_out;

  char* w = (char*)d_ws;
  unsigned* ctrs       = (unsigned*)(w + 0);        // 1025 barriers * 64B = 65600 (reserve 66048)
  unsigned short* xq   = (unsigned short*)(w + 66048);   // 131072
  unsigned short* hq   = (unsigned short*)(w + 197120);  // 65536
  unsigned short* rhq  = (unsigned short*)(w + 262656);  // 65536
  float* u_buf         = (float*)(w + 328192);           // 131072
  float* h_buf         = (float*)(w + 459264);           // 131072 -> total 590336 B

  hipFuncSetAttribute((const void*)gru_persistent,
                      hipFuncAttributeMaxDynamicSharedMemorySize, SMEM_BYTES);
  hipMemsetAsync(w, 0, 66048, stream);  // zero barrier counters each launch
  gru_persistent<<<NWG, TPB, SMEM_BYTES, stream>>>(
      x, h0, Wg, bg, Wc, bc, out, ctrs, xq, hq, rhq, u_buf, h_buf);
}

// Round 2
// 15490.750 us; speedup vs baseline: 1.8295x; 1.8295x over previous
//
#include <hip/hip_runtime.h>
#include <hip/hip_bf16.h>

#define B_ 32
#define T_ 512
#define D_ 1024
#define N_ 1024
#define NWG 192
#define NGATE 128
#define TPB 256
// LDS: weights [2][64][64][8] ushort = 131072 B, reduce 16 tiles*256 f32 = 16384 B, bias 64 B
#define SMEM_BYTES (131072 + 16384 + 64)

typedef __attribute__((ext_vector_type(8))) short short8v;
typedef __attribute__((ext_vector_type(4))) short short4v;
typedef __attribute__((ext_vector_type(4))) float f32x4;

__device__ __forceinline__ float bf2f(unsigned short u) {
  union { float f; unsigned int i; } c; c.i = ((unsigned int)u) << 16; return c.f;
}
__device__ __forceinline__ unsigned short f2bf(float f) {
  union { float f; unsigned int i; } c; c.f = f;
  unsigned int r = c.i + 0x7FFFu + ((c.i >> 16) & 1u);
  return (unsigned short)(r >> 16);
}

// Grid barrier, monotonic counters (zeroed each launch).
// Arrival: one RELEASE fetch_add (vmcnt drain + buffer_wbl2 + atomic at coherent point).
// Spin: RELAXED loads only — NO per-iteration cache maintenance (the acquire-in-loop
// buffer_inv storm was Round-1's 28 us/barrier).
// Exit: one ACQUIRE agent fence (single buffer_inv).
__device__ __forceinline__ void gbar(unsigned* ctrs, int idx) {
  __syncthreads();
  if (threadIdx.x == 0) {
    unsigned* c = ctrs + (size_t)idx * 16;
    __hip_atomic_fetch_add(c, 1u, __ATOMIC_RELEASE, __HIP_MEMORY_SCOPE_AGENT);
    int tries = 0;
    while (__hip_atomic_load(c, __ATOMIC_RELAXED, __HIP_MEMORY_SCOPE_AGENT) < NWG) {
      __builtin_amdgcn_s_sleep(1);
      if (++tries > (1 << 20)) break;  // deadlock valve; never hit normally
    }
    __builtin_amdgcn_fence(__ATOMIC_ACQUIRE, "agent");
  }
  __syncthreads();
}

// Compute a [32 x 16] partial tile over KS k-steps (KS*32 k-elements).
// A-fragment (16x16x32 bf16): lane l holds A[m=l&15][k], k = 4*(l>>4)+j (j=0..3)
// and 16+4*(l>>4)+j (j=4..7) within each 32-k step. B pre-arranged in LDS in
// fragment order, hi/lo split. Loads are issued for ALL k-steps before the MFMA
// chain so IF$ latency (~900cy) overlaps across KS in-flight loads.
template <int KS>
__device__ __forceinline__ void mfma_part(
    const unsigned short* __restrict__ src,  // [32][1024] A activations (bf16)
    int k0,                                  // element offset within row
    const unsigned short* __restrict__ ldsW, // [2][64][64][8]
    int ksg0,                                // global k-step base for B (0..63)
    float* ldsR, int slot0, int lane)
{
  const int kq = (lane >> 4) * 4;
#pragma unroll
  for (int mt = 0; mt < 2; ++mt) {
    const int m = mt * 16 + (lane & 15);
    const unsigned short* rowp = src + m * 1024 + k0;
    short8v areg[KS];
#pragma unroll
    for (int ks = 0; ks < KS; ++ks) {
      const int kl = ks * 32 + kq;
      short4v alo = *(const short4v*)(rowp + kl);
      short4v ahi = *(const short4v*)(rowp + kl + 16);
      areg[ks] = __builtin_shufflevector(alo, ahi, 0, 1, 2, 3, 4, 5, 6, 7);
    }
    f32x4 a = {0.f, 0.f, 0.f, 0.f};
#pragma unroll
    for (int ks = 0; ks < KS; ++ks) {
      const int ksg = ksg0 + ks;
      short8v bhi = *(const short8v*)(ldsW + ((size_t)(0 * 64 + ksg) * 64 + lane) * 8);
      short8v blo = *(const short8v*)(ldsW + ((size_t)(1 * 64 + ksg) * 64 + lane) * 8);
      a = __builtin_amdgcn_mfma_f32_16x16x32_bf16(areg[ks], bhi, a, 0, 0, 0);
      a = __builtin_amdgcn_mfma_f32_16x16x32_bf16(areg[ks], blo, a, 0, 0, 0);
    }
#pragma unroll
    for (int r = 0; r < 4; ++r)  // D layout: col=lane&15, row=4*(lane>>4)+r
      ldsR[(slot0 + mt) * 256 + (4 * (lane >> 4) + r) * 16 + (lane & 15)] = a[r];
  }
}

__global__ __launch_bounds__(TPB, 1) void gru_persistent(
    const float* __restrict__ x, const float* __restrict__ h0,
    const float* __restrict__ Wg, const float* __restrict__ bg,
    const float* __restrict__ Wc, const float* __restrict__ bc,
    float* __restrict__ out,
    unsigned* __restrict__ ctrs,
    unsigned short* __restrict__ xq,     // [2][32][1024] bf16 (double-buffered x_t)
    unsigned short* __restrict__ hq,     // [32][1024] bf16 h
    unsigned short* __restrict__ rhq,    // [32][1024] bf16 r*h
    float* __restrict__ u_buf,           // [32][1024] f32 u gate
    float* __restrict__ h_buf)           // [32][1024] f32 h
{
  const int wg = blockIdx.x;
  const int tid = threadIdx.x;
  const int lane = tid & 63;
  const int wv = tid >> 6;

  extern __shared__ char smem[];
  unsigned short* ldsW = (unsigned short*)smem;            // [2][64][64][8]
  float* ldsR = (float*)(smem + 131072);                   // [16][256]
  float* ldsBias = (float*)(smem + 131072 + 16384);        // [16]

  const bool is_gate = wg < NGATE;
  const int c0 = (is_gate ? wg : (wg - NGATE)) * 16;
  const float* Wsrc = is_gate ? Wg : Wc;
  const int ldw = is_gate ? 2 * N_ : N_;
  const float* bias = is_gate ? bg : bc;

  // ---- preload weight slice into LDS in MFMA-fragment order, hi/lo split bf16
  for (int i = tid; i < 64 * 64; i += TPB) {
    const int ks = i >> 6, l = i & 63;
    const int n = l & 15, kqp = (l >> 4) * 4;
#pragma unroll
    for (int j = 0; j < 8; ++j) {
      const int k = ks * 32 + ((j < 4) ? 0 : 16) + kqp + (j & 3);
      const float w = Wsrc[(size_t)k * ldw + c0 + n];
      const unsigned short hi = f2bf(w);
      const unsigned short lo = f2bf(w - bf2f(hi));
      ldsW[((size_t)(0 * 64 + ks) * 64 + l) * 8 + j] = hi;
      ldsW[((size_t)(1 * 64 + ks) * 64 + l) * 8 + j] = lo;
    }
  }
  if (tid < 16) ldsBias[tid] = bias[c0 + tid];

  // ---- init h/hq/xq[0] (gate WGs cover exactly 0..32767)
  {
    const int gidx = wg * TPB + tid;
    if (gidx < B_ * N_) {
      const float hv = h0[gidx];
      h_buf[gidx] = hv;
      hq[gidx] = f2bf(hv);
      const int b = gidx >> 10, d = gidx & 1023;
      xq[gidx] = f2bf(x[((size_t)b * T_) * D_ + d]);
    }
  }
  gbar(ctrs, 0);

  for (int t = 0; t < T_; ++t) {
    const unsigned short* xt = xq + (t & 1) * (B_ * D_);
    if (is_gate) {
      // ---- phase 1: gates for columns [c0, c0+16), full K=2048 over 4 waves
      mfma_part<16>((wv < 2) ? xt : hq, (wv & 1) * 512, ldsW, wv * 16,
                    ldsR, wv * 2, lane);
      __syncthreads();
#pragma unroll
      for (int mt = 0; mt < 2; ++mt) {
        const int rc = tid;
        float s = ldsR[(0 + mt) * 256 + rc] + ldsR[(2 + mt) * 256 + rc]
                + ldsR[(4 + mt) * 256 + rc] + ldsR[(6 + mt) * 256 + rc];
        const int row = rc >> 4, col = rc & 15;
        const int b = mt * 16 + row;
        const int colg = c0 + col;
        float pre = s + ldsBias[col];
        pre = fminf(fmaxf(pre, -30.f), 30.f);
        const float g = 1.f / (1.f + __expf(-pre));
        if (c0 < N_) {                       // r columns -> write r*h (bf16)
          const float hv = h_buf[b * N_ + colg];
          rhq[b * N_ + colg] = f2bf(g * hv);
        } else {                             // u columns -> write u (f32)
          u_buf[b * N_ + (colg - N_)] = g;
        }
      }
      gbar(ctrs, 1 + 2 * t);
      // ---- overlap: prefetch/convert x_{t+1} while cand WGs finish
      if (t + 1 < T_) {
        const int gidx = wg * TPB + tid;     // exactly 0..32767 over 128 gate WGs
        const int b = gidx >> 10, d = gidx & 1023;
        xq[((t + 1) & 1) * (B_ * D_) + gidx] =
            f2bf(x[((size_t)b * T_ + (t + 1)) * D_ + d]);
      }
      gbar(ctrs, 2 + 2 * t);
    } else {
      // ---- part A (off critical path): x_t @ Wc[k<1024], all 4 waves,
      //      overlapped with the gate phase (x_t is ready since last barrier)
      mfma_part<8>(xt, wv * 256, ldsW, wv * 8, ldsR, wv * 2, lane);
      gbar(ctrs, 1 + 2 * t);
      // ---- part B (critical path): (r*h) @ Wc[k>=1024], K=1024 over 4 waves
      mfma_part<8>(rhq, wv * 256, ldsW, 32 + wv * 8, ldsR, 8 + wv * 2, lane);
      __syncthreads();
#pragma unroll
      for (int mt = 0; mt < 2; ++mt) {
        const int rc = tid;
        float s = ldsR[(0 + mt) * 256 + rc]  + ldsR[(2 + mt) * 256 + rc]
                + ldsR[(4 + mt) * 256 + rc]  + ldsR[(6 + mt) * 256 + rc]
                + ldsR[(8 + mt) * 256 + rc]  + ldsR[(10 + mt) * 256 + rc]
                + ldsR[(12 + mt) * 256 + rc] + ldsR[(14 + mt) * 256 + rc];
        const int row = rc >> 4, col = rc & 15;
        const int b = mt * 16 + row;
        const int colg = c0 + col;
        float pre = s + ldsBias[col];
        pre = fminf(fmaxf(pre, -20.f), 20.f);
        const float e = __expf(2.f * pre);
        const float cv = (e - 1.f) / (e + 1.f);   // tanh
        const int hidx = b * N_ + colg;
        const float hv = h_buf[hidx];
        const float uv = u_buf[hidx];
        const float hn = uv * hv + (1.f - uv) * cv;
        h_buf[hidx] = hn;
        hq[hidx] = f2bf(hn);
        out[((size_t)b * T_ + t) * N_ + colg] = hn;
      }
      gbar(ctrs, 2 + 2 * t);
    }
  }
}

extern "C" void kernel_launch(void* const* d_in, const int* in_sizes, int n_in,
                              void* d_out, int out_size, void* d_ws, size_t ws_size,
                              hipStream_t stream) {
  const float* x  = (const float*)d_in[0];
  const float* h0 = (const float*)d_in[1];
  const float* Wg = (const float*)d_in[2];
  const float* bg = (const float*)d_in[3];
  const float* Wc = (const float*)d_in[4];
  const float* bc = (const float*)d_in[5];
  float* out = (float*)d_out;

  char* w = (char*)d_ws;
  unsigned* ctrs       = (unsigned*)(w + 0);             // 1025 barriers * 64B (reserve 66048)
  unsigned short* xq   = (unsigned short*)(w + 66048);   // 131072
  unsigned short* hq   = (unsigned short*)(w + 197120);  // 65536
  unsigned short* rhq  = (unsigned short*)(w + 262656);  // 65536
  float* u_buf         = (float*)(w + 328192);           // 131072
  float* h_buf         = (float*)(w + 459264);           // 131072 -> total 590336 B

  hipFuncSetAttribute((const void*)gru_persistent,
                      hipFuncAttributeMaxDynamicSharedMemorySize, SMEM_BYTES);
  hipMemsetAsync(w, 0, 66048, stream);  // zero barrier counters each launch
  gru_persistent<<<NWG, TPB, SMEM_BYTES, stream>>>(
      x, h0, Wg, bg, Wc, bc, out, ctrs, xq, hq, rhq, u_buf, h_buf);
}

// Round 3
// 5272.076 us; speedup vs baseline: 5.3756x; 2.9383x over previous
//
#include <hip/hip_runtime.h>
#include <hip/hip_bf16.h>

#define B_ 32
#define T_ 512
#define D_ 1024
#define N_ 1024
#define NWG 192
#define NGATE 128
#define TPB 256
// LDS: weights [2][64][64][8] ushort = 131072 B, reduce 16*256 f32 = 16384 B, bias 64 B
#define SMEM_BYTES (131072 + 16384 + 64)

typedef __attribute__((ext_vector_type(8))) short short8v;
typedef __attribute__((ext_vector_type(4))) float f32x4;

__device__ __forceinline__ float bf2f(unsigned short u) {
  union { float f; unsigned int i; } c; c.i = ((unsigned int)u) << 16; return c.f;
}
__device__ __forceinline__ unsigned short f2bf(float f) {
  union { float f; unsigned int i; } c; c.f = f;
  unsigned int r = c.i + 0x7FFFu + ((c.i >> 16) & 1u);
  return (unsigned short)(r >> 16);
}

// ---- direct-to-LLC (coherent point) accessors: bypass L1+L2 via sc0 sc1.
// All cross-WG shared data uses these, so the grid barrier needs NO fences.
__device__ __forceinline__ void st_bf16_sc(unsigned short* p, unsigned short v) {
  asm volatile("global_store_short %0, %1, off sc0 sc1"
               :: "v"((unsigned long long)p), "v"((unsigned)v) : "memory");
}
__device__ __forceinline__ void st_f32_sc(float* p, float v) {
  asm volatile("global_store_dword %0, %1, off sc0 sc1"
               :: "v"((unsigned long long)p), "v"(v) : "memory");
}
__device__ __forceinline__ void ld2_f32_sc(const float* p0, const float* p1,
                                           float& a, float& b) {
  asm volatile("global_load_dword %0, %2, off sc0 sc1\n\t"
               "global_load_dword %1, %3, off sc0 sc1\n\t"
               "s_waitcnt vmcnt(0)"
               : "=&v"(a), "=&v"(b)
               : "v"((unsigned long long)p0), "v"((unsigned long long)p1)
               : "memory");
}

// ---- two-level grid barrier, monotonic counters, 8 reusable slots.
// Leaf: 12 lines x 16 WGs (parallel far-atomics); last leaf arriver bumps root.
// No release/acquire fences needed: shared data moves via sc0sc1 (LLC-direct),
// and __syncthreads drains vmcnt (stores complete at coherent point).
__device__ __forceinline__ void gbar_arrive(unsigned* ctrs, int p, int wg) {
  __syncthreads();
  if (threadIdx.x == 0) {
    const int slot = p & 7, epoch = p >> 3;
    unsigned* L = ctrs + (size_t)(slot * 13 + (wg >> 4)) * 16;
    unsigned old = __hip_atomic_fetch_add(L, 1u, __ATOMIC_RELAXED, __HIP_MEMORY_SCOPE_AGENT);
    if (old == (unsigned)((epoch + 1) * 16 - 1)) {
      unsigned* R = ctrs + (size_t)(slot * 13 + 12) * 16;
      __hip_atomic_fetch_add(R, 1u, __ATOMIC_RELAXED, __HIP_MEMORY_SCOPE_AGENT);
    }
  }
}
__device__ __forceinline__ void gbar_wait(unsigned* ctrs, int p) {
  if (threadIdx.x == 0) {
    const int slot = p & 7, epoch = p >> 3;
    unsigned* R = ctrs + (size_t)(slot * 13 + 12) * 16;
    int tries = 0;
    while (__hip_atomic_load(R, __ATOMIC_RELAXED, __HIP_MEMORY_SCOPE_AGENT)
           < (unsigned)((epoch + 1) * 12)) {
      __builtin_amdgcn_s_sleep(1);
      if (++tries > (1 << 20)) break;  // deadlock valve; never hit normally
    }
  }
  __syncthreads();
}

// Fragment-order flat offset for a [32 rows][1024 k] A-matrix stored as
// [mt][ks][lane][j]: lane l holds A[m=mt*16+(l&15)][k], k = ks*32 + 16*(j>>2)
// + (l>>4)*4 + (j&3). Consumers read contiguous 16B per (mt,ks,lane).
__device__ __forceinline__ int frag_off(int m, int k) {
  const int mt = m >> 4, ks = k >> 5, kk = k & 31;
  const int l = (m & 15) + (((kk >> 2) & 3) << 4);
  const int j = (kk & 3) + ((kk >> 4) << 2);
  return ((mt * 32 + ks) * 64 + l) * 8 + j;
}

// [32 x 16] partial tile over KS k-steps. A read LLC-direct from a
// fragment-ordered buffer (fully coalesced dwordx4); B from LDS (frag order,
// hi/lo split-bf16). All loads issued first, one vmcnt(0), then MFMA chain.
template <int KS>
__device__ __forceinline__ void mfma_part(
    const unsigned short* __restrict__ fragbuf, int ks0,
    const unsigned short* __restrict__ ldsW, int ksg0,
    float* ldsR, int slot0, int lane)
{
  short8v areg[2][KS];
#pragma unroll
  for (int mt = 0; mt < 2; ++mt)
#pragma unroll
    for (int ks = 0; ks < KS; ++ks) {
      const unsigned short* p = fragbuf + ((size_t)((mt * 32 + ks0 + ks) * 64 + lane)) * 8;
      asm volatile("global_load_dwordx4 %0, %1, off sc0 sc1"
                   : "=v"(areg[mt][ks]) : "v"((unsigned long long)p) : "memory");
    }
  asm volatile("s_waitcnt vmcnt(0)" ::: "memory");
  __builtin_amdgcn_sched_barrier(0);  // rule #18: keep MFMAs after the waitcnt
#pragma unroll
  for (int mt = 0; mt < 2; ++mt) {
    f32x4 a = {0.f, 0.f, 0.f, 0.f};
#pragma unroll
    for (int ks = 0; ks < KS; ++ks) {
      const int ksg = ksg0 + ks;
      short8v bhi = *(const short8v*)(ldsW + ((size_t)(0 * 64 + ksg) * 64 + lane) * 8);
      short8v blo = *(const short8v*)(ldsW + ((size_t)(1 * 64 + ksg) * 64 + lane) * 8);
      a = __builtin_amdgcn_mfma_f32_16x16x32_bf16(areg[mt][ks], bhi, a, 0, 0, 0);
      a = __builtin_amdgcn_mfma_f32_16x16x32_bf16(areg[mt][ks], blo, a, 0, 0, 0);
    }
#pragma unroll
    for (int r = 0; r < 4; ++r)  // D layout: col=lane&15, row=4*(lane>>4)+r
      ldsR[(slot0 + mt) * 256 + (4 * (lane >> 4) + r) * 16 + (lane & 15)] = a[r];
  }
}

__global__ __launch_bounds__(TPB, 1) void gru_persistent(
    const float* __restrict__ x, const float* __restrict__ h0,
    const float* __restrict__ Wg, const float* __restrict__ bg,
    const float* __restrict__ Wc, const float* __restrict__ bc,
    float* __restrict__ out,
    unsigned* __restrict__ ctrs,
    unsigned short* __restrict__ xq,     // [2][frag 32x1024] bf16
    unsigned short* __restrict__ hq,     // [frag 32x1024] bf16 h
    unsigned short* __restrict__ rhq,    // [frag 32x1024] bf16 r*h
    float* __restrict__ u_buf,           // [32][1024] f32 u gate
    float* __restrict__ h_buf)           // [32][1024] f32 h (for r-gate readers)
{
  const int wg = blockIdx.x;
  const int tid = threadIdx.x;
  const int lane = tid & 63;
  const int wv = tid >> 6;

  extern __shared__ char smem[];
  unsigned short* ldsW = (unsigned short*)smem;            // [2][64][64][8]
  float* ldsR = (float*)(smem + 131072);                   // [16][256]
  float* ldsBias = (float*)(smem + 131072 + 16384);        // [16]

  const bool is_gate = wg < NGATE;
  const int c0 = (is_gate ? wg : (wg - NGATE)) * 16;
  const float* Wsrc = is_gate ? Wg : Wc;
  const int ldw = is_gate ? 2 * N_ : N_;
  const float* bias = is_gate ? bg : bc;

  // ---- preload weight slice into LDS in MFMA-fragment order, hi/lo split bf16
  for (int i = tid; i < 64 * 64; i += TPB) {
    const int ks = i >> 6, l = i & 63;
    const int n = l & 15, kqp = (l >> 4) * 4;
#pragma unroll
    for (int j = 0; j < 8; ++j) {
      const int k = ks * 32 + ((j < 4) ? 0 : 16) + kqp + (j & 3);
      const float w = Wsrc[(size_t)k * ldw + c0 + n];
      const unsigned short hi = f2bf(w);
      const unsigned short lo = f2bf(w - bf2f(hi));
      ldsW[((size_t)(0 * 64 + ks) * 64 + l) * 8 + j] = hi;
      ldsW[((size_t)(1 * 64 + ks) * 64 + l) * 8 + j] = lo;
    }
  }
  if (tid < 16) ldsBias[tid] = bias[c0 + tid];

  // ---- init: gate WGs fill xq[0] and hq (frag order, one elem per thread);
  //      cand WGs own h: registers + h_buf copy for r-gate readers.
  float hreg0 = 0.f, hreg1 = 0.f;
  if (is_gate) {
    const int g = wg * TPB + tid;           // 0..32767, = frag flat index
    const int j = g & 7, l = (g >> 3) & 63, ks = (g >> 9) & 31, mt = g >> 14;
    const int b = mt * 16 + (l & 15);
    const int k = ks * 32 + ((j >> 2) << 4) + ((l >> 4) << 2) + (j & 3);
    st_bf16_sc(xq + g, f2bf(x[((size_t)b * T_) * D_ + k]));
    st_bf16_sc(hq + g, f2bf(h0[b * N_ + k]));
  } else {
    const int colg = c0 + (tid & 15);
    const int b0 = tid >> 4, b1 = 16 + (tid >> 4);
    hreg0 = h0[b0 * N_ + colg];
    hreg1 = h0[b1 * N_ + colg];
    st_f32_sc(h_buf + b0 * N_ + colg, hreg0);
    st_f32_sc(h_buf + b1 * N_ + colg, hreg1);
  }
  gbar_arrive(ctrs, 0, wg);
  gbar_wait(ctrs, 0);

  for (int t = 0; t < T_; ++t) {
    const unsigned short* xt = xq + (t & 1) * 32768;
    if (is_gate) {
      // gates = sigmoid([x_t, h] @ Wg + bg), K=2048 over 4 waves
      mfma_part<16>((wv < 2) ? xt : hq, (wv & 1) * 16, ldsW, wv * 16,
                    ldsR, wv * 2, lane);
      __syncthreads();
      {
        const int col = tid & 15, row = tid >> 4;
        const int colg = c0 + col;
        const int b0 = row, b1 = 16 + row;
        float s0 = ldsR[0 * 256 + tid] + ldsR[2 * 256 + tid]
                 + ldsR[4 * 256 + tid] + ldsR[6 * 256 + tid];
        float s1 = ldsR[1 * 256 + tid] + ldsR[3 * 256 + tid]
                 + ldsR[5 * 256 + tid] + ldsR[7 * 256 + tid];
        float p0 = fminf(fmaxf(s0 + ldsBias[col], -30.f), 30.f);
        float p1 = fminf(fmaxf(s1 + ldsBias[col], -30.f), 30.f);
        const float g0 = 1.f / (1.f + __expf(-p0));
        const float g1 = 1.f / (1.f + __expf(-p1));
        if (c0 < N_) {                       // r columns -> r*h (bf16, frag order)
          float hv0, hv1;
          ld2_f32_sc(h_buf + b0 * N_ + colg, h_buf + b1 * N_ + colg, hv0, hv1);
          st_bf16_sc(rhq + frag_off(b0, colg), f2bf(g0 * hv0));
          st_bf16_sc(rhq + frag_off(b1, colg), f2bf(g1 * hv1));
        } else {                             // u columns -> u (f32)
          st_f32_sc(u_buf + b0 * N_ + (colg - N_), g0);
          st_f32_sc(u_buf + b1 * N_ + (colg - N_), g1);
        }
      }
      gbar_arrive(ctrs, 1 + 2 * t, wg);      // arrive-only: nothing below reads
                                             // what cand produces this phase
      if (t + 1 < T_) {                      // prefetch x_{t+1} into other buffer
        const int g = wg * TPB + tid;
        const int j = g & 7, l = (g >> 3) & 63, ks = (g >> 9) & 31, mt = g >> 14;
        const int b = mt * 16 + (l & 15);
        const int k = ks * 32 + ((j >> 2) << 4) + ((l >> 4) << 2) + (j & 3);
        st_bf16_sc(xq + ((t + 1) & 1) * 32768 + g,
                   f2bf(x[((size_t)b * T_ + (t + 1)) * D_ + k]));
      }
      gbar_arrive(ctrs, 2 + 2 * t, wg);
      gbar_wait(ctrs, 2 + 2 * t);            // need hq/h_buf from cand
    } else {
      // part A (off critical path): x_t @ Wc[k<1024]
      mfma_part<8>(xt, wv * 8, ldsW, wv * 8, ldsR, wv * 2, lane);
      gbar_arrive(ctrs, 1 + 2 * t, wg);
      gbar_wait(ctrs, 1 + 2 * t);            // need rhq (and u) from gates
      // part B (critical path): (r*h) @ Wc[k>=1024]
      mfma_part<8>(rhq, wv * 8, ldsW, 32 + wv * 8, ldsR, 8 + wv * 2, lane);
      __syncthreads();
      {
        const int col = tid & 15, row = tid >> 4;
        const int colg = c0 + col;
        const int b0 = row, b1 = 16 + row;
        float s0 = ldsR[0 * 256 + tid] + ldsR[2 * 256 + tid]
                 + ldsR[4 * 256 + tid] + ldsR[6 * 256 + tid]
                 + ldsR[8 * 256 + tid] + ldsR[10 * 256 + tid]
                 + ldsR[12 * 256 + tid] + ldsR[14 * 256 + tid];
        float s1 = ldsR[1 * 256 + tid] + ldsR[3 * 256 + tid]
                 + ldsR[5 * 256 + tid] + ldsR[7 * 256 + tid]
                 + ldsR[9 * 256 + tid] + ldsR[11 * 256 + tid]
                 + ldsR[13 * 256 + tid] + ldsR[15 * 256 + tid];
        float uv0, uv1;
        ld2_f32_sc(u_buf + b0 * N_ + colg, u_buf + b1 * N_ + colg, uv0, uv1);
        float p0 = fminf(fmaxf(s0 + ldsBias[col], -20.f), 20.f);
        float p1 = fminf(fmaxf(s1 + ldsBias[col], -20.f), 20.f);
        const float e0 = __expf(2.f * p0), e1 = __expf(2.f * p1);
        const float c0v = (e0 - 1.f) / (e0 + 1.f);
        const float c1v = (e1 - 1.f) / (e1 + 1.f);
        const float hn0 = uv0 * hreg0 + (1.f - uv0) * c0v;
        const float hn1 = uv1 * hreg1 + (1.f - uv1) * c1v;
        hreg0 = hn0; hreg1 = hn1;
        st_bf16_sc(hq + frag_off(b0, colg), f2bf(hn0));
        st_bf16_sc(hq + frag_off(b1, colg), f2bf(hn1));
        st_f32_sc(h_buf + b0 * N_ + colg, hn0);
        st_f32_sc(h_buf + b1 * N_ + colg, hn1);
        out[((size_t)b0 * T_ + t) * N_ + colg] = hn0;   // cached store (output)
        out[((size_t)b1 * T_ + t) * N_ + colg] = hn1;
      }
      gbar_arrive(ctrs, 2 + 2 * t, wg);
      gbar_wait(ctrs, 2 + 2 * t);            // need xq[(t+1)&1] from gates
    }
  }
}

extern "C" void kernel_launch(void* const* d_in, const int* in_sizes, int n_in,
                              void* d_out, int out_size, void* d_ws, size_t ws_size,
                              hipStream_t stream) {
  const float* x  = (const float*)d_in[0];
  const float* h0 = (const float*)d_in[1];
  const float* Wg = (const float*)d_in[2];
  const float* bg = (const float*)d_in[3];
  const float* Wc = (const float*)d_in[4];
  const float* bc = (const float*)d_in[5];
  float* out = (float*)d_out;

  char* w = (char*)d_ws;
  unsigned* ctrs       = (unsigned*)(w + 0);             // 8 slots*13 lines*64B = 6656 (reserve 8192)
  unsigned short* xq   = (unsigned short*)(w + 8192);    // 131072
  unsigned short* hq   = (unsigned short*)(w + 139264);  // 65536
  unsigned short* rhq  = (unsigned short*)(w + 204800);  // 65536
  float* u_buf         = (float*)(w + 270336);           // 131072
  float* h_buf         = (float*)(w + 401408);           // 131072 -> total 532480 B

  hipFuncSetAttribute((const void*)gru_persistent,
                      hipFuncAttributeMaxDynamicSharedMemorySize, SMEM_BYTES);
  hipMemsetAsync(w, 0, 8192, stream);  // zero barrier counters each launch
  gru_persistent<<<NWG, TPB, SMEM_BYTES, stream>>>(
      x, h0, Wg, bg, Wc, bc, out, ctrs, xq, hq, rhq, u_buf, h_buf);
}